// Round 8
// baseline (16.215 us; speedup 1.0000x reference)
//
#include <hip/hip_runtime.h>
#include <math.h>

#define S2 64
#define HH 128
#define WW 128
#define BB 16
#define TIK 0.05f
#define NG 17           // g=0..15: dual-uu blocks; g=16: uu=32 block = batch finisher
#define NBLK (BB * NG)  // 272 blocks
#define MAGIC1 0x5EEDF00Du
#define MAGIC2 0xC0FFEE42u

// complex rotate: (c,s) *= (cr,sr)
#define ROT(c, s, cr, sr)                           \
    {                                               \
        const float _cn = fmaf(c, cr, -(s) * (sr)); \
        s = fmaf(s, cr, (c) * (sr));                \
        c = _cn;                                    \
    }

// acc (float4) += sc * v (float4)
#define FMA4(acc, sc, v)                \
    acc.x = fmaf(sc, v.x, acc.x);       \
    acc.y = fmaf(sc, v.y, acc.y);       \
    acc.z = fmaf(sc, v.z, acc.z);       \
    acc.w = fmaf(sc, v.w, acc.w);

__device__ __forceinline__ void consume_flag(unsigned int* f, unsigned int magic) {
    while (__hip_atomic_exchange(f, 0u, __ATOMIC_ACQUIRE,
                                 __HIP_MEMORY_SCOPE_AGENT) != magic)
        __builtin_amdgcn_s_sleep(1);
}

// SINGLE dispatch. One block per (b,g), 256 threads. Two-level fan-in:
// g<16 publish partial -> batch finisher (g==16) -> global finisher (b==15).
// Self-resetting double-magic flags (R5 protocol, proven correct; R5's cost
// was 527 serial flag ops — here the critical path has ~32).
__global__ __launch_bounds__(256) void chf_fused(const float* __restrict__ dnn,
                                                 const float* __restrict__ chf,
                                                 float* __restrict__ part,      // [BB*16]
                                                 unsigned int* __restrict__ pf1,
                                                 unsigned int* __restrict__ pf2,
                                                 float* __restrict__ bres,      // [BB-1]
                                                 unsigned int* __restrict__ bf1,
                                                 unsigned int* __restrict__ bf2,
                                                 float* __restrict__ out) {
    const int bid = blockIdx.x;
    const int b = bid / NG;
    const int g = bid - b * NG;      // 0..16
    const int t = threadIdx.x;       // 0..255
    const bool dual = (g < 16);
    const int uu0 = dual ? (g << 1) : 32;
    const int uu1 = (g << 1) + 1;    // only meaningful when dual

    __shared__ float a2r0[8 * WW], a2i0[8 * WW], a2r1[8 * WW], a2i1[8 * WW];
    __shared__ float crw0[WW], ciw0[WW], crw1[WW], ciw1[WW];
    __shared__ float prc0[256], prs0[256], pic0[256], pis0[256];
    __shared__ float prc1[256], prs1[256], pic1[256], pis1[256];
    __shared__ float gather[16];
    __shared__ float batch_r[BB - 1];

    const float fu0 = (float)(uu0 - 32) * TIK;
    const float fu1 = (float)(uu1 - 32) * TIK;

    // Prefetch chf rows (epilogue operands).
    float2 cf0 = make_float2(0.f, 0.f), cfm0 = make_float2(0.f, 0.f);
    float2 cf1 = make_float2(0.f, 0.f), cfm1 = make_float2(0.f, 0.f);
    if (t < 64) {
        cf0 = *(const float2*)(chf + ((((size_t)b * S2 + uu0) * S2 + t) * 2));
        if (uu0 >= 1 && uu0 <= 31)
            cfm0 = *(const float2*)(chf + ((((size_t)b * S2 + (64 - uu0)) * S2 + t) * 2));
        if (dual) {
            cf1 = *(const float2*)(chf + ((((size_t)b * S2 + uu1) * S2 + t) * 2));
            cfm1 = *(const float2*)(chf + ((((size_t)b * S2 + (64 - uu1)) * S2 + t) * 2));
        }
    }

    // ---- Phase A: 8 h-groups x 16 h; 4 rotators cover both fu's ----
    {
        const int hg = t >> 5;        // 0..7
        const int w4 = t & 31;        // float4 column index
        const float4* drow = (const float4*)(dnn + (size_t)b * HH * WW);

        const float base = (float)(hg * 16) + 0.5f;
        float c00 = __cosf(fu0 * base), s00 = __sinf(fu0 * base);
        const float cA = __cosf(fu0), sA = __sinf(fu0);
        float c01 = c00, s01 = s00;
        ROT(c01, s01, cA, sA);
        const float c2A = fmaf(cA, cA, -sA * sA), s2A = 2.0f * sA * cA;

        float c10 = 0.f, s10 = 0.f, c11 = 0.f, s11 = 0.f;
        float c2B = 1.f, s2B = 0.f;
        if (dual) {
            c10 = __cosf(fu1 * base); s10 = __sinf(fu1 * base);
            const float cB = __cosf(fu1), sB = __sinf(fu1);
            c11 = c10; s11 = s10;
            ROT(c11, s11, cB, sB);
            c2B = fmaf(cB, cB, -sB * sB); s2B = 2.0f * sB * cB;
        }

        float4 ar0 = {0, 0, 0, 0}, ai0 = {0, 0, 0, 0};
        float4 ar1 = {0, 0, 0, 0}, ai1 = {0, 0, 0, 0};
#pragma unroll
        for (int j = 0; j < 8; ++j) {
            const int h = hg * 16 + 2 * j;
            const float4 d0 = drow[h * (WW / 4) + w4];
            const float4 d1 = drow[(h + 1) * (WW / 4) + w4];
            FMA4(ar0, c00, d0); FMA4(ai0, s00, d0);
            FMA4(ar0, c01, d1); FMA4(ai0, s01, d1);
            FMA4(ar1, c10, d0); FMA4(ai1, s10, d0);
            FMA4(ar1, c11, d1); FMA4(ai1, s11, d1);
            ROT(c00, s00, c2A, s2A);
            ROT(c01, s01, c2A, s2A);
            ROT(c10, s10, c2B, s2B);
            ROT(c11, s11, c2B, s2B);
        }
        const int idx = hg * WW + w4 * 4;
        *(float4*)&a2r0[idx] = ar0;
        *(float4*)&a2i0[idx] = ai0;
        *(float4*)&a2r1[idx] = ar1;
        *(float4*)&a2i1[idx] = ai1;
    }
    __syncthreads();

    if (t < WW) {
        float sr0 = 0, si0 = 0, sr1 = 0, si1 = 0;
#pragma unroll
        for (int k = 0; k < 8; ++k) {
            sr0 += a2r0[k * WW + t];
            si0 += a2i0[k * WW + t];
            sr1 += a2r1[k * WW + t];
            si1 += a2i1[k * WW + t];
        }
        crw0[t] = sr0; ciw0[t] = si0;
        crw1[t] = sr1; ciw1[t] = si1;
    }
    __syncthreads();

    // ---- Phase B: shared v-rotators feed both uu's cross-sums ----
    {
        const int v = t & 63;
        const int q = t >> 6;  // quarter 0..3
        const int w0 = q * 32;
        const float fv = (float)(v - 32) * TIK;

        const float a0 = fv * ((float)w0 + 0.5f);
        float c0 = __cosf(a0), s0 = __sinf(a0);
        const float cfv = __cosf(fv), sfv = __sinf(fv);
        float c1 = c0, s1 = s0; ROT(c1, s1, cfv, sfv);
        float c2 = c1, s2 = s1; ROT(c2, s2, cfv, sfv);
        float c3 = c2, s3 = s2; ROT(c3, s3, cfv, sfv);
        const float c2f = fmaf(cfv, cfv, -sfv * sfv);
        const float s2f = 2.0f * sfv * cfv;
        const float c4f = fmaf(c2f, c2f, -s2f * s2f);
        const float s4f = 2.0f * s2f * c2f;

        float rc0 = 0, rs0 = 0, ic0 = 0, is0 = 0;
        float rc1 = 0, rs1 = 0, ic1 = 0, is1 = 0;
#define BSTEP(CK, SK, W)                                          \
        {                                                         \
            const float cr0v = crw0[W], ci0v = ciw0[W];           \
            const float cr1v = crw1[W], ci1v = ciw1[W];           \
            rc0 = fmaf(CK, cr0v, rc0); rs0 = fmaf(SK, cr0v, rs0); \
            ic0 = fmaf(CK, ci0v, ic0); is0 = fmaf(SK, ci0v, is0); \
            rc1 = fmaf(CK, cr1v, rc1); rs1 = fmaf(SK, cr1v, rs1); \
            ic1 = fmaf(CK, ci1v, ic1); is1 = fmaf(SK, ci1v, is1); \
        }
#pragma unroll
        for (int j = 0; j < 8; ++j) {
            const int w = w0 + 4 * j;
            BSTEP(c0, s0, w);
            BSTEP(c1, s1, w + 1);
            BSTEP(c2, s2, w + 2);
            BSTEP(c3, s3, w + 3);
            ROT(c0, s0, c4f, s4f);
            ROT(c1, s1, c4f, s4f);
            ROT(c2, s2, c4f, s4f);
            ROT(c3, s3, c4f, s4f);
        }
#undef BSTEP
        prc0[t] = rc0; prs0[t] = rs0; pic0[t] = ic0; pis0[t] = is0;
        prc1[t] = rc1; prs1[t] = rs1; pic1[t] = ic1; pis1[t] = is1;
    }
    __syncthreads();

    // ---- Combine quarters, emit owned u rows, squared error ----
    float sq = 0.0f;
    if (t < 64) {
        const float rc = prc0[t] + prc0[t + 64] + prc0[t + 128] + prc0[t + 192];
        const float rs = prs0[t] + prs0[t + 64] + prs0[t + 128] + prs0[t + 192];
        const float ic = pic0[t] + pic0[t + 64] + pic0[t + 128] + pic0[t + 192];
        const float is_ = pis0[t] + pis0[t + 64] + pis0[t + 128] + pis0[t + 192];

        const float d0 = (rc - is_) - cf0.x;   // real(uu0)
        const float d1 = (rs + ic) - cf0.y;    // img(uu0)
        sq = fmaf(d0, d0, d1 * d1);
        if (uu0 >= 1 && uu0 <= 31) {
            const float d2 = (rc + is_) - cfm0.x;
            const float d3 = (rs - ic) - cfm0.y;
            sq = fmaf(d2, d2, sq);
            sq = fmaf(d3, d3, sq);
        }

        if (dual) {
            const float rcB = prc1[t] + prc1[t + 64] + prc1[t + 128] + prc1[t + 192];
            const float rsB = prs1[t] + prs1[t + 64] + prs1[t + 128] + prs1[t + 192];
            const float icB = pic1[t] + pic1[t + 64] + pic1[t + 128] + pic1[t + 192];
            const float isB = pis1[t] + pis1[t + 64] + pis1[t + 128] + pis1[t + 192];

            const float e0 = (rcB - isB) - cf1.x;
            const float e1 = (rsB + icB) - cf1.y;
            sq = fmaf(e0, e0, sq);
            sq = fmaf(e1, e1, sq);
            const float e2 = (rcB + isB) - cfm1.x;  // uu1 always in [1,31]
            const float e3 = (rsB - icB) - cfm1.y;
            sq = fmaf(e2, e2, sq);
            sq = fmaf(e3, e3, sq);
        }
#pragma unroll
        for (int off = 32; off; off >>= 1)
            sq += __shfl_down(sq, off, 64);
    }
    // sq now valid in thread 0 only.

    // ---- Level 1: producers publish to their batch finisher ----
    if (dual) {
        if (t == 0) {
            const int slot = b * 16 + g;
            __hip_atomic_store(&part[slot], sq, __ATOMIC_RELAXED, __HIP_MEMORY_SCOPE_AGENT);
            __hip_atomic_store(&pf1[slot], MAGIC1, __ATOMIC_RELEASE, __HIP_MEMORY_SCOPE_AGENT);
            __hip_atomic_store(&pf2[slot], MAGIC2, __ATOMIC_RELEASE, __HIP_MEMORY_SCOPE_AGENT);
        }
        return;
    }

    // ---- Batch finisher (g == 16): gather 16 sibling partials ----
    if (t < 16) {
        const int slot = b * 16 + t;
        consume_flag(&pf1[slot], MAGIC1);
        consume_flag(&pf2[slot], MAGIC2);
        gather[t] = __hip_atomic_load(&part[slot], __ATOMIC_RELAXED, __HIP_MEMORY_SCOPE_AGENT);
    }
    __syncthreads();

    if (b < BB - 1) {
        if (t == 0) {
            float acc = sq;
#pragma unroll
            for (int i = 0; i < 16; ++i) acc += gather[i];
            const float r = sqrtf(acc);
            __hip_atomic_store(&bres[b], r, __ATOMIC_RELAXED, __HIP_MEMORY_SCOPE_AGENT);
            __hip_atomic_store(&bf1[b], MAGIC1, __ATOMIC_RELEASE, __HIP_MEMORY_SCOPE_AGENT);
            __hip_atomic_store(&bf2[b], MAGIC2, __ATOMIC_RELEASE, __HIP_MEMORY_SCOPE_AGENT);
        }
        return;
    }

    // ---- Global finisher (b == 15, g == 16) ----
    if (t < BB - 1) {
        consume_flag(&bf1[t], MAGIC1);
        consume_flag(&bf2[t], MAGIC2);
        batch_r[t] = __hip_atomic_load(&bres[t], __ATOMIC_RELAXED, __HIP_MEMORY_SCOPE_AGENT);
    }
    __syncthreads();
    if (t == 0) {
        float acc = sq;
#pragma unroll
        for (int i = 0; i < 16; ++i) acc += gather[i];
        float tot = sqrtf(acc);  // batch 15's result
#pragma unroll
        for (int i = 0; i < BB - 1; ++i) tot += batch_r[i];
        out[0] = tot * (TIK / (float)BB);
    }
}

extern "C" void kernel_launch(void* const* d_in, const int* in_sizes, int n_in,
                              void* d_out, int out_size, void* d_ws, size_t ws_size,
                              hipStream_t stream) {
    const float* dnn = (const float*)d_in[0];  // (16,128,128) f32
    const float* chf = (const float*)d_in[1];  // (16,64,64,2) f32
    float* out = (float*)d_out;                // scalar f32

    float* part = (float*)d_ws;                          // [0,256)
    unsigned int* pf1 = (unsigned int*)d_ws + 256;       // [256,512)
    unsigned int* pf2 = (unsigned int*)d_ws + 512;       // [512,768)
    float* bres = (float*)d_ws + 768;                    // [768,784)
    unsigned int* bf1 = (unsigned int*)d_ws + 784;       // [784,800)
    unsigned int* bf2 = (unsigned int*)d_ws + 800;       // [800,816)

    chf_fused<<<dim3(NBLK), dim3(256), 0, stream>>>(dnn, chf, part, pf1, pf2,
                                                    bres, bf1, bf2, out);
}

// Round 9
// 11.528 us; speedup vs baseline: 1.4066x; 1.4066x over previous
//
#include <hip/hip_runtime.h>
#include <math.h>

#define S2 64
#define HH 128
#define WW 128
#define BB 16
#define TIK 0.05f
#define NU 33           // uu = 0..32; uu=1..31 also emit mirror row u = 64-uu
#define NBLK (BB * NU)  // 528 blocks

// complex rotate: (c,s) *= (cr,sr)
#define ROT(c, s, cr, sr)                           \
    {                                               \
        const float _cn = fmaf(c, cr, -(s) * (sr)); \
        s = fmaf(s, cr, (c) * (sr));                \
        c = _cn;                                    \
    }

// Two dispatches (R3/R5/R8: any in-kernel cross-XCD handoff level costs ~3us,
// a graph node only ~1.4us). One block per (b,uu), 256 threads.
// XCD-affinity swizzle: bid = uu*16 + b, so all 33 blocks of batch b have
// bid % 16 == b -> same XCD under round-robin dispatch; the 64KB dnn slice is
// fetched into ONE L2 instead of eight (perf heuristic only).
__global__ __launch_bounds__(256) void chf_main(const float* __restrict__ dnn,
                                                const float* __restrict__ chf,
                                                float* __restrict__ partials) {
    const int bid = blockIdx.x;
    const int b = bid & 15;          // 0..15  (same-XCD group)
    const int uu = bid >> 4;         // 0..32
    const int t = threadIdx.x;       // 0..255

    __shared__ float a2r[8 * WW], a2i[8 * WW];  // phase-A h-group partials
    __shared__ float crw[WW], ciw[WW];          // stage-A outputs
    __shared__ float prc[256], prs[256], pic[256], pis[256];

    const float fu = (float)(uu - 32) * TIK;

    // Prefetch chf early (epilogue operand).
    float2 cf = make_float2(0.f, 0.f), cfm = make_float2(0.f, 0.f);
    if (t < 64) {
        cf = *(const float2*)(chf + ((((size_t)b * S2 + uu) * S2 + t) * 2));
        if (uu >= 1 && uu <= 31)
            cfm = *(const float2*)(chf + ((((size_t)b * S2 + (64 - uu)) * S2 + t) * 2));
    }

    // ---- Phase A: 8 h-groups x 16 h; 2 rotators (step 2*fu), no LDS trig ----
    {
        const int hg = t >> 5;          // 0..7
        const int w4 = (t & 31) << 2;   // 0,4,...,124
        const float4* drow = (const float4*)(dnn + (size_t)b * HH * WW);

        const float a0 = fu * ((float)(hg * 16) + 0.5f);
        float c0 = __cosf(a0), s0 = __sinf(a0);          // h = hg*16 (even j)
        const float cfu = __cosf(fu), sfu = __sinf(fu);
        float c1 = c0, s1 = s0;
        ROT(c1, s1, cfu, sfu);                           // h = hg*16+1 (odd j)
        const float c2s = fmaf(cfu, cfu, -sfu * sfu);    // cos(2fu)
        const float s2s = 2.0f * sfu * cfu;              // sin(2fu)

        float ar0 = 0, ar1 = 0, ar2 = 0, ar3 = 0;
        float ai0 = 0, ai1 = 0, ai2 = 0, ai3 = 0;
#pragma unroll
        for (int j = 0; j < 8; ++j) {
            const int h = hg * 16 + 2 * j;
            const float4 d0 = drow[h * (WW / 4) + (w4 >> 2)];
            const float4 d1 = drow[(h + 1) * (WW / 4) + (w4 >> 2)];
            ar0 = fmaf(c0, d0.x, ar0); ai0 = fmaf(s0, d0.x, ai0);
            ar1 = fmaf(c0, d0.y, ar1); ai1 = fmaf(s0, d0.y, ai1);
            ar2 = fmaf(c0, d0.z, ar2); ai2 = fmaf(s0, d0.z, ai2);
            ar3 = fmaf(c0, d0.w, ar3); ai3 = fmaf(s0, d0.w, ai3);
            ar0 = fmaf(c1, d1.x, ar0); ai0 = fmaf(s1, d1.x, ai0);
            ar1 = fmaf(c1, d1.y, ar1); ai1 = fmaf(s1, d1.y, ai1);
            ar2 = fmaf(c1, d1.z, ar2); ai2 = fmaf(s1, d1.z, ai2);
            ar3 = fmaf(c1, d1.w, ar3); ai3 = fmaf(s1, d1.w, ai3);
            ROT(c0, s0, c2s, s2s);
            ROT(c1, s1, c2s, s2s);
        }
        *(float4*)&a2r[hg * WW + w4] = make_float4(ar0, ar1, ar2, ar3);
        *(float4*)&a2i[hg * WW + w4] = make_float4(ai0, ai1, ai2, ai3);
    }
    __syncthreads();

    if (t < WW) {
        float sr = 0, si = 0;
#pragma unroll
        for (int g = 0; g < 8; ++g) {
            sr += a2r[g * WW + t];
            si += a2i[g * WW + t];
        }
        crw[t] = sr;
        ciw[t] = si;
    }
    __syncthreads();

    // ---- Phase B: 4 rotators (step 4*fv), serial chain 8 steps ----
    {
        const int v = t & 63;
        const int q = t >> 6;  // quarter 0..3
        const int w0 = q * 32;
        const float fv = (float)(v - 32) * TIK;

        const float a0 = fv * ((float)w0 + 0.5f);
        float c0 = __cosf(a0), s0 = __sinf(a0);
        const float cfv = __cosf(fv), sfv = __sinf(fv);
        float c1 = c0, s1 = s0; ROT(c1, s1, cfv, sfv);
        float c2 = c1, s2 = s1; ROT(c2, s2, cfv, sfv);
        float c3 = c2, s3 = s2; ROT(c3, s3, cfv, sfv);
        const float c2f = fmaf(cfv, cfv, -sfv * sfv);  // cos(2fv)
        const float s2f = 2.0f * sfv * cfv;            // sin(2fv)
        const float c4f = fmaf(c2f, c2f, -s2f * s2f);  // cos(4fv)
        const float s4f = 2.0f * s2f * c2f;            // sin(4fv)

        float rc = 0, rs = 0, ic = 0, is_ = 0;
#pragma unroll
        for (int j = 0; j < 8; ++j) {
            const int w = w0 + 4 * j;
            float cr, ci;
            cr = crw[w];     ci = ciw[w];
            rc = fmaf(c0, cr, rc); rs = fmaf(s0, cr, rs);
            ic = fmaf(c0, ci, ic); is_ = fmaf(s0, ci, is_);
            cr = crw[w + 1]; ci = ciw[w + 1];
            rc = fmaf(c1, cr, rc); rs = fmaf(s1, cr, rs);
            ic = fmaf(c1, ci, ic); is_ = fmaf(s1, ci, is_);
            cr = crw[w + 2]; ci = ciw[w + 2];
            rc = fmaf(c2, cr, rc); rs = fmaf(s2, cr, rs);
            ic = fmaf(c2, ci, ic); is_ = fmaf(s2, ci, is_);
            cr = crw[w + 3]; ci = ciw[w + 3];
            rc = fmaf(c3, cr, rc); rs = fmaf(s3, cr, rs);
            ic = fmaf(c3, ci, ic); is_ = fmaf(s3, ci, is_);
            ROT(c0, s0, c4f, s4f);
            ROT(c1, s1, c4f, s4f);
            ROT(c2, s2, c4f, s4f);
            ROT(c3, s3, c4f, s4f);
        }
        prc[t] = rc; prs[t] = rs; pic[t] = ic; pis[t] = is_;
    }
    __syncthreads();

    // ---- Combine quarters, emit u and mirror 64-u, squared error ----
    if (t < 64) {
        const float rc = prc[t] + prc[t + 64] + prc[t + 128] + prc[t + 192];
        const float rs = prs[t] + prs[t + 64] + prs[t + 128] + prs[t + 192];
        const float ic = pic[t] + pic[t + 64] + pic[t + 128] + pic[t + 192];
        const float is_ = pis[t] + pis[t + 64] + pis[t + 128] + pis[t + 192];

        const float d0 = (rc - is_) - cf.x;   // real(u)
        const float d1 = (rs + ic) - cf.y;    // img(u)
        float sq = fmaf(d0, d0, d1 * d1);

        if (uu >= 1 && uu <= 31) {
            const float d2 = (rc + is_) - cfm.x;  // real(64-u)
            const float d3 = (rs - ic) - cfm.y;   // img(64-u)
            sq = fmaf(d2, d2, sq);
            sq = fmaf(d3, d3, sq);
        }
#pragma unroll
        for (int off = 32; off; off >>= 1)
            sq += __shfl_down(sq, off, 64);
        if (t == 0) partials[bid] = sq;
    }
}

// 1 block x 1024 threads: wave b reduces the 33 partials of batch b.
// partials layout: partials[uu*16 + b] (XCD-swizzled bid).
__global__ __launch_bounds__(1024) void chf_final(const float* __restrict__ partials,
                                                  float* __restrict__ out) {
    const int t = threadIdx.x;   // 0..1023
    const int b = t >> 6;        // wave index = batch
    const int l = t & 63;
    __shared__ float red[BB];
    float v = (l < NU) ? partials[l * BB + b] : 0.0f;
#pragma unroll
    for (int off = 32; off; off >>= 1)
        v += __shfl_down(v, off, 64);
    if (l == 0) red[b] = sqrtf(v);
    __syncthreads();
    if (t == 0) {
        float acc = 0;
#pragma unroll
        for (int i = 0; i < BB; ++i) acc += red[i];
        out[0] = acc * (TIK / (float)BB);
    }
}

extern "C" void kernel_launch(void* const* d_in, const int* in_sizes, int n_in,
                              void* d_out, int out_size, void* d_ws, size_t ws_size,
                              hipStream_t stream) {
    const float* dnn = (const float*)d_in[0];  // (16,128,128) f32
    const float* chf = (const float*)d_in[1];  // (16,64,64,2) f32
    float* out = (float*)d_out;                // scalar f32
    float* partials = (float*)d_ws;            // NBLK floats, fully overwritten

    chf_main<<<dim3(NBLK), dim3(256), 0, stream>>>(dnn, chf, partials);
    chf_final<<<dim3(1), dim3(1024), 0, stream>>>(partials, out);
}